// Round 1
// 1278.701 us; speedup vs baseline: 1.0180x; 1.0180x over previous
//
#include <hip/hip_runtime.h>
#include <cmath>

// Weighted log-softmax NLL:
//   out = -(1/B) * sum_b (2*a1_freq[b])^gramma * ( x[b,y0[b]] - logsumexp(x[b,:]) )
//
// V2: branchless streaming pass. Instead of the branchy online-logsumexp
// (data-dependent branch + loop-carried exp chains -> latency-bound at ~640us,
// 4x the 166us memory roofline), we stream with:
//   - 4 independent fmax accumulators for the row max (robustness check only)
//   - 4 independent Sigma exp(v) accumulators (NO max subtraction)
// For |rowmax| <= 60 the unshifted f32 sum can neither overflow (needs ~78)
// nor underflow-to-zero (needs ~-87), so lse = log(S) directly.
// A block-uniform fallback re-pass with exp(v - M) handles |M| > 60 (never
// taken for this input; preserves general correctness).

__global__ __launch_bounds__(256) void ce_loss_kernel(
    const float* __restrict__ x,
    const int*   __restrict__ y0,
    const float* __restrict__ a1,
    const int*   __restrict__ gramma,
    float*       __restrict__ out,
    int B, int C)
{
    constexpr int BS = 256;
    const int row = blockIdx.x;
    const float* xrow = x + (size_t)row * (size_t)C;

    const int n4 = C >> 2;
    const float4* xr4 = reinterpret_cast<const float4*>(xrow);

    // Branchless streaming: independent accumulators break all dependence
    // chains except the cheap per-accumulator fmax/add (2 cyc each).
    float m0 = -INFINITY, m1 = -INFINITY, m2 = -INFINITY, m3 = -INFINITY;
    float s0 = 0.f, s1 = 0.f, s2 = 0.f, s3 = 0.f;

    #pragma unroll 4
    for (int i = threadIdx.x; i < n4; i += BS) {
        float4 v = xr4[i];
        m0 = fmaxf(m0, v.x); s0 += __expf(v.x);
        m1 = fmaxf(m1, v.y); s1 += __expf(v.y);
        m2 = fmaxf(m2, v.z); s2 += __expf(v.z);
        m3 = fmaxf(m3, v.w); s3 += __expf(v.w);
    }
    // tail (C % 4 == 0 here; kept for safety)
    for (int i = (n4 << 2) + threadIdx.x; i < C; i += BS) {
        float v = xrow[i];
        m0 = fmaxf(m0, v); s0 += __expf(v);
    }

    float m = fmaxf(fmaxf(m0, m1), fmaxf(m2, m3));
    float s = (s0 + s1) + (s2 + s3);

    // wave-64 reduction (sum and max are now independent reductions)
    #pragma unroll
    for (int off = 32; off >= 1; off >>= 1) {
        m = fmaxf(m, __shfl_down(m, off, 64));
        s += __shfl_down(s, off, 64);
    }

    // cross-wave reduction via LDS (256 threads = 4 waves)
    __shared__ float sm[4], ss[4], bM;
    const int lane = threadIdx.x & 63;
    const int wid  = threadIdx.x >> 6;
    if (lane == 0) { sm[wid] = m; ss[wid] = s; }
    __syncthreads();

    float S = 0.f;
    if (threadIdx.x == 0) {
        float M0 = fmaxf(fmaxf(sm[0], sm[1]), fmaxf(sm[2], sm[3]));
        S = (ss[0] + ss[1]) + (ss[2] + ss[3]);
        bM = M0;
    }
    __syncthreads();
    const float M = bM;                       // block-uniform row max
    const bool fallback = (M > 60.0f) || (M < -60.0f);

    if (fallback) {
        // Rare numerically-extreme row: re-stream with shifted exponent.
        float t0 = 0.f, t1 = 0.f, t2 = 0.f, t3 = 0.f;
        for (int i = threadIdx.x; i < n4; i += BS) {
            float4 v = xr4[i];
            t0 += __expf(v.x - M); t1 += __expf(v.y - M);
            t2 += __expf(v.z - M); t3 += __expf(v.w - M);
        }
        for (int i = (n4 << 2) + threadIdx.x; i < C; i += BS)
            t0 += __expf(xrow[i] - M);
        float t = (t0 + t1) + (t2 + t3);
        #pragma unroll
        for (int off = 32; off >= 1; off >>= 1) t += __shfl_down(t, off, 64);
        if (lane == 0) ss[wid] = t;
        __syncthreads();
        if (threadIdx.x == 0) S = (ss[0] + ss[1]) + (ss[2] + ss[3]);
    }

    if (threadIdx.x == 0) {
        const float lse = fallback ? (M + logf(S)) : logf(S);
        const int   idx = y0[row];
        const float xy  = xrow[idx];
        const float a   = a1[row];
        const int   g   = gramma[0];
        const float w   = (g == 1) ? (2.0f * a) : powf(2.0f * a, (float)g);
        const float contrib = -w * (xy - lse) / (float)B;
        atomicAdd(out, contrib);
    }
}

extern "C" void kernel_launch(void* const* d_in, const int* in_sizes, int n_in,
                              void* d_out, int out_size, void* d_ws, size_t ws_size,
                              hipStream_t stream) {
    const float* x      = (const float*)d_in[0];
    const int*   y0     = (const int*)d_in[1];
    const float* a1     = (const float*)d_in[2];
    const int*   gramma = (const int*)d_in[3];
    float*       out    = (float*)d_out;

    const int B = in_sizes[1];          // 8192
    const int C = in_sizes[0] / B;      // 32000

    // d_out is poisoned before every timed replay; zero it (capture-safe).
    hipMemsetAsync(out, 0, sizeof(float), stream);
    ce_loss_kernel<<<B, 256, 0, stream>>>(x, y0, a1, gramma, out, B, C);
}